// Round 1
// baseline (477.811 us; speedup 1.0000x reference)
//
#include <hip/hip_runtime.h>

#define SEQ 2048
#define HID 1024
#define NHEAD 16
#define HDIM 64
#define NB 4
#define NTOK (NB * SEQ)   // 8192
#define NQKV (3 * HID)    // 3072

typedef __attribute__((ext_vector_type(8))) short bf16x8;
typedef __attribute__((ext_vector_type(4))) float f32x4;

// ---------- helpers ----------

__device__ __forceinline__ void glds16(const void* g, void* l) {
  // async global->LDS, 16B per lane; LDS dest = wave-uniform base + lane*16
  __builtin_amdgcn_global_load_lds(
      (const __attribute__((address_space(1))) void*)g,
      (__attribute__((address_space(3))) void*)l, 16, 0, 0);
}

__device__ __forceinline__ ushort f2bf(float f) {
  union { float f; unsigned int u; } a; a.f = f;
  unsigned int u = a.u;
  return (ushort)((u + 0x7fffu + ((u >> 16) & 1u)) >> 16);  // RNE
}

// ---------- 1. fused LayerNorm -> bf16 ----------

__global__ __launch_bounds__(256) void ln_kernel(const float* __restrict__ x,
                                                 const float* __restrict__ g,
                                                 const float* __restrict__ be,
                                                 ushort* __restrict__ y) {
  const int row = blockIdx.x;
  const int tid = threadIdx.x;
  const float4 v = ((const float4*)(x + (size_t)row * HID))[tid];
  float s  = v.x + v.y + v.z + v.w;
  float sq = v.x * v.x + v.y * v.y + v.z * v.z + v.w * v.w;
  for (int o = 1; o < 64; o <<= 1) { s += __shfl_xor(s, o, 64); sq += __shfl_xor(sq, o, 64); }
  __shared__ float as_[4], aq_[4];
  const int wv = tid >> 6;
  if ((tid & 63) == 0) { as_[wv] = s; aq_[wv] = sq; }
  __syncthreads();
  s  = as_[0] + as_[1] + as_[2] + as_[3];
  sq = aq_[0] + aq_[1] + aq_[2] + aq_[3];
  const float mu  = s * (1.0f / HID);
  const float var = sq * (1.0f / HID) - mu * mu;
  const float rs  = rsqrtf(var + 1e-12f);
  const float4 gv = ((const float4*)g)[tid];
  const float4 bv = ((const float4*)be)[tid];
  ushort4 o;
  o.x = f2bf((v.x - mu) * rs * gv.x + bv.x);
  o.y = f2bf((v.y - mu) * rs * gv.y + bv.y);
  o.z = f2bf((v.z - mu) * rs * gv.z + bv.z);
  o.w = f2bf((v.w - mu) * rs * gv.w + bv.w);
  ((ushort4*)(y + (size_t)row * HID))[tid] = o;
}

// ---------- 2. transpose + fp32->bf16 convert:  W[R][C] -> WT[C][R] ----------

__global__ __launch_bounds__(256) void transpose_cvt(const float* __restrict__ W,
                                                     ushort* __restrict__ WT,
                                                     int R, int C) {
  __shared__ float t[32][33];
  const int c0 = blockIdx.x * 32, r0 = blockIdx.y * 32;
  const int tx = threadIdx.x & 31, ty = threadIdx.x >> 5;
  for (int j = 0; j < 4; ++j)
    t[ty + j * 8][tx] = W[(size_t)(r0 + ty + j * 8) * C + c0 + tx];
  __syncthreads();
  for (int j = 0; j < 4; ++j)
    WT[(size_t)(c0 + ty + j * 8) * R + r0 + tx] = f2bf(t[tx][ty + j * 8]);
}

// ---------- 3. GEMM  C[M][N] = A[M][K] * Bt[N][K]^T  (bf16 in, fp32 acc) ----------
// MODE 0: C_bf16 = acc + bias        (QKV projection)
// MODE 1: C_f32  = acc + bias + res  (out projection + residual)

template <int MODE>
__global__ __launch_bounds__(256) void gemm_bt(const ushort* __restrict__ A,
                                               const ushort* __restrict__ Bt,
                                               const float* __restrict__ bias,
                                               const float* __restrict__ resid,
                                               ushort* __restrict__ obf,
                                               float* __restrict__ of32,
                                               int M, int N, int K) {
  __shared__ ushort As[128 * 64];  // 8 chunks/row, XOR-swizzled
  __shared__ ushort Bs[128 * 64];
  const int tid = threadIdx.x;
  const int lane = tid & 63, wv = tid >> 6;
  const int q = lane >> 4, li = lane & 15;
  const int m0 = blockIdx.y * 128, n0 = blockIdx.x * 128;
  const int wm = (wv >> 1) * 64, wn = (wv & 1) * 64;
  f32x4 acc[4][4] = {};

  for (int kb = 0; kb < K; kb += 64) {
    for (int e = 0; e < 4; ++e) {
      const int chunk = (wv * 4 + e) * 64 + lane;
      const int row = chunk >> 3, slot = chunk & 7;
      const int kc = slot ^ (row & 7);
      glds16(A  + (size_t)(m0 + row) * K + kb + kc * 8, As + (wv * 4 + e) * 512);
      glds16(Bt + (size_t)(n0 + row) * K + kb + kc * 8, Bs + (wv * 4 + e) * 512);
    }
    __syncthreads();
    for (int ks = 0; ks < 2; ++ks) {
      const int kc = ks * 4 + q;
      bf16x8 af[4], bfr[4];
      for (int mi = 0; mi < 4; ++mi) {
        const int row = wm + mi * 16 + li;
        af[mi] = *(const bf16x8*)(As + (row * 8 + (kc ^ (row & 7))) * 8);
      }
      for (int ni = 0; ni < 4; ++ni) {
        const int row = wn + ni * 16 + li;
        bfr[ni] = *(const bf16x8*)(Bs + (row * 8 + (kc ^ (row & 7))) * 8);
      }
      for (int mi = 0; mi < 4; ++mi)
        for (int ni = 0; ni < 4; ++ni)
          acc[mi][ni] = __builtin_amdgcn_mfma_f32_16x16x32_bf16(af[mi], bfr[ni], acc[mi][ni], 0, 0, 0);
    }
    __syncthreads();
  }

  for (int ni = 0; ni < 4; ++ni) {
    const int col = n0 + wn + ni * 16 + li;
    const float bv = bias[col];
    for (int mi = 0; mi < 4; ++mi) {
      for (int r = 0; r < 4; ++r) {
        const int row = m0 + wm + mi * 16 + q * 4 + r;
        const float v = acc[mi][ni][r] + bv;
        if (MODE == 0) obf[(size_t)row * N + col] = f2bf(v);
        else           of32[(size_t)row * N + col] = v + resid[(size_t)row * N + col];
      }
    }
  }
}

// ---------- 4. flash attention (q-tile 128, kv-tile 64, D=64, bf16 MFMA) ----------

__global__ __launch_bounds__(256) void flash_attn(const ushort* __restrict__ qkv,
                                                  const float* __restrict__ mask,
                                                  ushort* __restrict__ outa) {
  __shared__ ushort Qs[128 * 64];     // [q][d] CPR=8 swizzled
  __shared__ ushort Ks[64 * 64];      // [kv][d]
  __shared__ ushort Vts[64 * 64];     // [d][kv] (transposed during staging)
  __shared__ ushort Ps[4][32 * 64];   // per-wave P, [q][kv]
  const int tid = threadIdx.x, lane = tid & 63, wv = tid >> 6;
  const int q = lane >> 4, li = lane & 15;
  const int qt = blockIdx.x, h = blockIdx.y, b = blockIdx.z;
  const size_t tokbase = (size_t)b * SEQ;

  // stage Q once
  for (int e = 0; e < 4; ++e) {
    const int chunk = (wv * 4 + e) * 64 + lane;
    const int row = chunk >> 3, slot = chunk & 7;
    const int kc = slot ^ (row & 7);
    glds16(qkv + (tokbase + qt * 128 + row) * NQKV + h * HDIM + kc * 8,
           Qs + (wv * 4 + e) * 512);
  }

  f32x4 accO[2][4] = {};
  float m_st[2][4], l_st[2][4];
  for (int a = 0; a < 2; ++a)
    for (int r = 0; r < 4; ++r) { m_st[a][r] = -1e30f; l_st[a][r] = 0.f; }

  for (int t = 0; t < SEQ / 64; ++t) {
    const int kv0 = t * 64;
    // stage K
    for (int e = 0; e < 2; ++e) {
      const int chunk = (wv * 2 + e) * 64 + lane;
      const int row = chunk >> 3, slot = chunk & 7;
      const int kc = slot ^ (row & 7);
      glds16(qkv + (tokbase + kv0 + row) * NQKV + HID + h * HDIM + kc * 8,
             Ks + (wv * 2 + e) * 512);
    }
    // stage V transposed (scalar LDS writes)
    for (int c = tid; c < 512; c += 256) {
      const int kv = c >> 3, cd = c & 7;
      union { uint4 u; ushort s[8]; } vv;
      vv.u = *(const uint4*)(qkv + (tokbase + kv0 + kv) * NQKV + 2 * HID + h * HDIM + cd * 8);
      for (int j = 0; j < 8; ++j) {
        const int d = cd * 8 + j;
        Vts[(d * 8 + ((kv >> 3) ^ (d & 7))) * 8 + (kv & 7)] = vv.s[j];
      }
    }
    __syncthreads();

    // S = Q K^T
    f32x4 sc[2][4] = {};
    for (int ks = 0; ks < 2; ++ks) {
      const int kc = ks * 4 + q;
      bf16x8 af[2], bfr[4];
      for (int mt = 0; mt < 2; ++mt) {
        const int row = wv * 32 + mt * 16 + li;
        af[mt] = *(const bf16x8*)(Qs + (row * 8 + (kc ^ (row & 7))) * 8);
      }
      for (int nt = 0; nt < 4; ++nt) {
        const int row = nt * 16 + li;
        bfr[nt] = *(const bf16x8*)(Ks + (row * 8 + (kc ^ (row & 7))) * 8);
      }
      for (int mt = 0; mt < 2; ++mt)
        for (int nt = 0; nt < 4; ++nt)
          sc[mt][nt] = __builtin_amdgcn_mfma_f32_16x16x32_bf16(af[mt], bfr[nt], sc[mt][nt], 0, 0, 0);
    }

    // online softmax (C-layout: lane owns rows q*4+r, cols li+16*nt)
    float maskv[4];
    for (int nt = 0; nt < 4; ++nt) maskv[nt] = mask[b * SEQ + kv0 + nt * 16 + li];
    for (int mt = 0; mt < 2; ++mt) {
      for (int r = 0; r < 4; ++r) {
        float vvv[4]; float mx = -1e30f;
        for (int nt = 0; nt < 4; ++nt) {
          vvv[nt] = sc[mt][nt][r] * 0.125f + maskv[nt];
          mx = fmaxf(mx, vvv[nt]);
        }
        for (int o2 = 1; o2 < 16; o2 <<= 1) mx = fmaxf(mx, __shfl_xor(mx, o2, 64));
        const float mn = fmaxf(m_st[mt][r], mx);
        const float alpha = __expf(m_st[mt][r] - mn);
        float rsum = 0.f;
        ushort pb[4];
        for (int nt = 0; nt < 4; ++nt) {
          const float p = __expf(vvv[nt] - mn);
          rsum += p; pb[nt] = f2bf(p);
        }
        for (int o2 = 1; o2 < 16; o2 <<= 1) rsum += __shfl_xor(rsum, o2, 64);
        m_st[mt][r] = mn;
        l_st[mt][r] = l_st[mt][r] * alpha + rsum;
        for (int nd = 0; nd < 4; ++nd) accO[mt][nd][r] *= alpha;
        const int prow = mt * 16 + q * 4 + r;
        for (int nt = 0; nt < 4; ++nt) {
          const int col = nt * 16 + li;
          Ps[wv][(prow * 8 + ((col >> 3) ^ (prow & 7))) * 8 + (col & 7)] = pb[nt];
        }
      }
    }
    __syncthreads();  // P visible (and K reads drained)

    // O += P V
    for (int ks = 0; ks < 2; ++ks) {
      const int kc = ks * 4 + q;
      bf16x8 af[2], bfr[4];
      for (int mt = 0; mt < 2; ++mt) {
        const int row = mt * 16 + li;
        af[mt] = *(const bf16x8*)(&Ps[wv][(row * 8 + (kc ^ (row & 7))) * 8]);
      }
      for (int nd = 0; nd < 4; ++nd) {
        const int row = nd * 16 + li;  // d index
        bfr[nd] = *(const bf16x8*)(Vts + (row * 8 + (kc ^ (row & 7))) * 8);
      }
      for (int mt = 0; mt < 2; ++mt)
        for (int nd = 0; nd < 4; ++nd)
          accO[mt][nd] = __builtin_amdgcn_mfma_f32_16x16x32_bf16(af[mt], bfr[nd], accO[mt][nd], 0, 0, 0);
    }
    __syncthreads();  // V reads drained before next staging
  }

  // epilogue: normalize and store bf16
  for (int mt = 0; mt < 2; ++mt) {
    for (int r = 0; r < 4; ++r) {
      const size_t tok = tokbase + qt * 128 + wv * 32 + mt * 16 + q * 4 + r;
      const float inv = 1.0f / l_st[mt][r];
      for (int nd = 0; nd < 4; ++nd) {
        const int d = nd * 16 + li;
        outa[tok * HID + h * HDIM + d] = f2bf(accO[mt][nd][r] * inv);
      }
    }
  }
}

// ---------- launch ----------

extern "C" void kernel_launch(void* const* d_in, const int* in_sizes, int n_in,
                              void* d_out, int out_size, void* d_ws, size_t ws_size,
                              hipStream_t stream) {
  const float* hidden = (const float*)d_in[0];
  const float* mask   = (const float*)d_in[1];
  const float* gamma  = (const float*)d_in[2];
  const float* beta   = (const float*)d_in[3];
  const float* Wqkv   = (const float*)d_in[4];
  const float* bqkv   = (const float*)d_in[5];
  const float* Wout   = (const float*)d_in[6];
  const float* bout   = (const float*)d_in[7];
  float* out = (float*)d_out;

  char* ws = (char*)d_ws;
  ushort* x_bf  = (ushort*)(ws);                       // 16 MB
  ushort* wqkvT = (ushort*)(ws + ((size_t)16 << 20));  //  6 MB
  ushort* woutT = (ushort*)(ws + ((size_t)22 << 20));  //  2 MB
  ushort* qkvb  = (ushort*)(ws + ((size_t)24 << 20));  // 48 MB
  ushort* attnb = (ushort*)(ws + ((size_t)72 << 20));  // 16 MB

  ln_kernel<<<NTOK, 256, 0, stream>>>(hidden, gamma, beta, x_bf);
  transpose_cvt<<<dim3(NQKV / 32, HID / 32), 256, 0, stream>>>(Wqkv, wqkvT, HID, NQKV);
  transpose_cvt<<<dim3(HID / 32, HID / 32), 256, 0, stream>>>(Wout, woutT, HID, HID);
  gemm_bt<0><<<dim3(NQKV / 128, NTOK / 128), 256, 0, stream>>>(
      x_bf, wqkvT, bqkv, nullptr, qkvb, nullptr, NTOK, NQKV, HID);
  flash_attn<<<dim3(SEQ / 128, NHEAD, NB), 256, 0, stream>>>(qkvb, mask, attnb);
  gemm_bt<1><<<dim3(HID / 128, NTOK / 128), 256, 0, stream>>>(
      attnb, woutT, bout, hidden, nullptr, out, NTOK, HID, HID);
}

// Round 2
// 363.610 us; speedup vs baseline: 1.3141x; 1.3141x over previous
//
#include <hip/hip_runtime.h>

#define SEQ 2048
#define HID 1024
#define NHEAD 16
#define HDIM 64
#define NB 4
#define NTOK (NB * SEQ)   // 8192
#define NQKV (3 * HID)    // 3072

typedef __attribute__((ext_vector_type(8))) short bf16x8;
typedef __attribute__((ext_vector_type(4))) float f32x4;

// ---------- helpers ----------

__device__ __forceinline__ void glds16(const void* g, void* l) {
  // async global->LDS, 16B per lane; LDS dest = wave-uniform base + lane*16
  __builtin_amdgcn_global_load_lds(
      (const __attribute__((address_space(1))) void*)g,
      (__attribute__((address_space(3))) void*)l, 16, 0, 0);
}

__device__ __forceinline__ ushort f2bf(float f) {
  union { float f; unsigned int u; } a; a.f = f;
  unsigned int u = a.u;
  return (ushort)((u + 0x7fffu + ((u >> 16) & 1u)) >> 16);  // RNE
}

__device__ __forceinline__ unsigned int pack2bf(float a, float b) {
  return (unsigned int)f2bf(a) | ((unsigned int)f2bf(b) << 16);
}

// ---------- 1. fused LayerNorm -> bf16 ----------

__global__ __launch_bounds__(256) void ln_kernel(const float* __restrict__ x,
                                                 const float* __restrict__ g,
                                                 const float* __restrict__ be,
                                                 ushort* __restrict__ y) {
  const int row = blockIdx.x;
  const int tid = threadIdx.x;
  const float4 v = ((const float4*)(x + (size_t)row * HID))[tid];
  float s  = v.x + v.y + v.z + v.w;
  float sq = v.x * v.x + v.y * v.y + v.z * v.z + v.w * v.w;
  for (int o = 1; o < 64; o <<= 1) { s += __shfl_xor(s, o, 64); sq += __shfl_xor(sq, o, 64); }
  __shared__ float as_[4], aq_[4];
  const int wv = tid >> 6;
  if ((tid & 63) == 0) { as_[wv] = s; aq_[wv] = sq; }
  __syncthreads();
  s  = as_[0] + as_[1] + as_[2] + as_[3];
  sq = aq_[0] + aq_[1] + aq_[2] + aq_[3];
  const float mu  = s * (1.0f / HID);
  const float var = sq * (1.0f / HID) - mu * mu;
  const float rs  = rsqrtf(var + 1e-12f);
  const float4 gv = ((const float4*)g)[tid];
  const float4 bv = ((const float4*)be)[tid];
  ushort4 o;
  o.x = f2bf((v.x - mu) * rs * gv.x + bv.x);
  o.y = f2bf((v.y - mu) * rs * gv.y + bv.y);
  o.z = f2bf((v.z - mu) * rs * gv.z + bv.z);
  o.w = f2bf((v.w - mu) * rs * gv.w + bv.w);
  ((ushort4*)(y + (size_t)row * HID))[tid] = o;
}

// ---------- 2. transpose + fp32->bf16 convert:  W[R][C] -> WT[C][R] ----------

__global__ __launch_bounds__(256) void transpose_cvt(const float* __restrict__ W,
                                                     ushort* __restrict__ WT,
                                                     int R, int C) {
  __shared__ float t[32][33];
  const int c0 = blockIdx.x * 32, r0 = blockIdx.y * 32;
  const int tx = threadIdx.x & 31, ty = threadIdx.x >> 5;
  for (int j = 0; j < 4; ++j)
    t[ty + j * 8][tx] = W[(size_t)(r0 + ty + j * 8) * C + c0 + tx];
  __syncthreads();
  for (int j = 0; j < 4; ++j)
    WT[(size_t)(c0 + ty + j * 8) * R + r0 + tx] = f2bf(t[tx][ty + j * 8]);
}

// ---------- 2b. V transpose: qkv V-region [tok][h*64+d] -> Vt[b][h][d][s] ----------

__global__ __launch_bounds__(256) void v_transpose(const ushort* __restrict__ qkv,
                                                   ushort* __restrict__ vt) {
  __shared__ ushort t[64][66];
  const int s0 = blockIdx.x * 64, h = blockIdx.y, b = blockIdx.z;
  const size_t tokbase = (size_t)b * SEQ;
  for (int e = 0; e < 2; ++e) {
    const int c = e * 256 + threadIdx.x;
    const int sr = c >> 3, dc = c & 7;
    *(uint4*)&t[sr][dc * 8] =
        *(const uint4*)(qkv + (tokbase + s0 + sr) * NQKV + 2 * HID + h * HDIM + dc * 8);
  }
  __syncthreads();
  for (int e = 0; e < 2; ++e) {
    const int c = e * 256 + threadIdx.x;
    const int dr = c >> 3, sc = c & 7;
    ushort tmp[8];
    for (int j = 0; j < 8; ++j) tmp[j] = t[sc * 8 + j][dr];
    *(uint4*)(vt + ((size_t)(b * NHEAD + h) * HDIM + dr) * SEQ + s0 + sc * 8) = *(uint4*)tmp;
  }
}

// ---------- 3. GEMM  C[M][N] = A[M][K] * Bt[N][K]^T  (bf16 in, fp32 acc) ----------
// MODE 0: C_bf16 = acc + bias        (QKV projection)
// MODE 1: C_f32  = acc + bias + res  (out projection + residual)

template <int MODE>
__global__ __launch_bounds__(256) void gemm_bt(const ushort* __restrict__ A,
                                               const ushort* __restrict__ Bt,
                                               const float* __restrict__ bias,
                                               const float* __restrict__ resid,
                                               ushort* __restrict__ obf,
                                               float* __restrict__ of32,
                                               int M, int N, int K) {
  __shared__ ushort As[128 * 64];  // 8 chunks/row, XOR-swizzled
  __shared__ ushort Bs[128 * 64];
  const int tid = threadIdx.x;
  const int lane = tid & 63, wv = tid >> 6;
  const int q = lane >> 4, li = lane & 15;
  const int m0 = blockIdx.y * 128, n0 = blockIdx.x * 128;
  const int wm = (wv >> 1) * 64, wn = (wv & 1) * 64;
  f32x4 acc[4][4] = {};

  for (int kb = 0; kb < K; kb += 64) {
    for (int e = 0; e < 4; ++e) {
      const int chunk = (wv * 4 + e) * 64 + lane;
      const int row = chunk >> 3, slot = chunk & 7;
      const int kc = slot ^ (row & 7);
      glds16(A  + (size_t)(m0 + row) * K + kb + kc * 8, As + (wv * 4 + e) * 512);
      glds16(Bt + (size_t)(n0 + row) * K + kb + kc * 8, Bs + (wv * 4 + e) * 512);
    }
    __syncthreads();
    for (int ks = 0; ks < 2; ++ks) {
      const int kc = ks * 4 + q;
      bf16x8 af[4], bfr[4];
      for (int mi = 0; mi < 4; ++mi) {
        const int row = wm + mi * 16 + li;
        af[mi] = *(const bf16x8*)(As + (row * 8 + (kc ^ (row & 7))) * 8);
      }
      for (int ni = 0; ni < 4; ++ni) {
        const int row = wn + ni * 16 + li;
        bfr[ni] = *(const bf16x8*)(Bs + (row * 8 + (kc ^ (row & 7))) * 8);
      }
      for (int mi = 0; mi < 4; ++mi)
        for (int ni = 0; ni < 4; ++ni)
          acc[mi][ni] = __builtin_amdgcn_mfma_f32_16x16x32_bf16(af[mi], bfr[ni], acc[mi][ni], 0, 0, 0);
    }
    __syncthreads();
  }

  for (int ni = 0; ni < 4; ++ni) {
    const int col = n0 + wn + ni * 16 + li;
    const float bv = bias[col];
    for (int mi = 0; mi < 4; ++mi) {
      for (int r = 0; r < 4; ++r) {
        const int row = m0 + wm + mi * 16 + q * 4 + r;
        const float v = acc[mi][ni][r] + bv;
        if (MODE == 0) obf[(size_t)row * N + col] = f2bf(v);
        else           of32[(size_t)row * N + col] = v + resid[(size_t)row * N + col];
      }
    }
  }
}

// ---------- 4. flash attention, S^T formulation ----------
// Per block: q-tile 128 (wave: 32), kv-tile 64. LDS: Q[128][64], K[64][64] (kv
// rows bit-permuted by sigma), Vt[64][kv 64]. S^T = K·Q^T; with sigma chosen so
// P^T's C-layout registers ARE the A-fragment of O += P·V. No P LDS round-trip.
// sigma: LDS row m holds physical kv = (m&0b100011)|((m&0b1100)<<1)|((m&0b10000)>>2)

__global__ __launch_bounds__(256) void flash_attn(const ushort* __restrict__ qkv,
                                                  const ushort* __restrict__ vt,
                                                  const float* __restrict__ mask,
                                                  ushort* __restrict__ outa) {
  __shared__ ushort Qs[128 * 64];   // 16 KB
  __shared__ ushort Ks[64 * 64];    //  8 KB
  __shared__ ushort Vts[64 * 64];   //  8 KB  ([d][kv])
  const int tid = threadIdx.x, lane = tid & 63, wv = tid >> 6;
  const int quad = lane >> 4, li = lane & 15;
  const int wq = wv * 32;
  const int qt = blockIdx.x, h = blockIdx.y, b = blockIdx.z;
  const size_t tokbase = (size_t)b * SEQ;
  const size_t vtbase = (size_t)(b * NHEAD + h) * HDIM * SEQ;

  // stage Q once
  for (int e = 0; e < 4; ++e) {
    const int c = (wv * 4 + e) * 64 + lane;
    const int row = c >> 3, slot = c & 7;
    const int kc = slot ^ (row & 7);
    glds16(qkv + (tokbase + qt * 128 + row) * NQKV + h * HDIM + kc * 8,
           Qs + (wv * 4 + e) * 512);
  }

  f32x4 accO[2][4] = {};            // [mq][nd], rows q, cols d (C-layout)
  float m_st[2] = {-1e30f, -1e30f}; // per q-col (nq*16+li)
  float l_st[2] = {0.f, 0.f};

  for (int t = 0; t < SEQ / 64; ++t) {
    const int kv0 = t * 64;
    // stage K (sigma-permuted rows) and V^T
    for (int e = 0; e < 2; ++e) {
      const int c = (wv * 2 + e) * 64 + lane;
      const int row = c >> 3, slot = c & 7;
      const int kc = slot ^ (row & 7);
      const int gkv = (row & 0x23) | ((row & 0x0c) << 1) | ((row & 0x10) >> 2);
      glds16(qkv + (tokbase + kv0 + gkv) * NQKV + HID + h * HDIM + kc * 8,
             Ks + (wv * 2 + e) * 512);
      glds16(vt + vtbase + (size_t)row * SEQ + kv0 + kc * 8,
             Vts + (wv * 2 + e) * 512);
    }
    // mask values for this lane's S^T rows (sigma-inverse applied)
    float4 mk[4];
    for (int mkv = 0; mkv < 4; ++mkv)
      mk[mkv] = *(const float4*)(mask + b * SEQ + kv0 + (mkv >> 1) * 32 + quad * 8 + (mkv & 1) * 4);
    __syncthreads();

    // S^T = K · Q^T   (rows kv, cols q)
    f32x4 sc[2][4] = {};  // [nq][mkv]
    for (int ks = 0; ks < 2; ++ks) {
      const int kc = ks * 4 + quad;
      bf16x8 kf[4], qf[2];
      for (int mkv = 0; mkv < 4; ++mkv) {
        const int row = mkv * 16 + li;
        kf[mkv] = *(const bf16x8*)(Ks + (row * 8 + (kc ^ (row & 7))) * 8);
      }
      for (int nq = 0; nq < 2; ++nq) {
        const int row = wq + nq * 16 + li;
        qf[nq] = *(const bf16x8*)(Qs + (row * 8 + (kc ^ (row & 7))) * 8);
      }
      for (int nq = 0; nq < 2; ++nq)
        for (int mkv = 0; mkv < 4; ++mkv)
          sc[nq][mkv] = __builtin_amdgcn_mfma_f32_16x16x32_bf16(kf[mkv], qf[nq], sc[nq][mkv], 0, 0, 0);
    }

    // online softmax: per lane, 2 q-cols x 16 kv values (in-lane + 2 shuffles)
    unsigned int pk[2][4][2];  // packed bf16 P, [nq][mkv][r-pair]
    float alpha[2];
    for (int nq = 0; nq < 2; ++nq) {
      float vv[4][4];
      float mx = -1e30f;
      for (int mkv = 0; mkv < 4; ++mkv)
        for (int r = 0; r < 4; ++r) {
          const float v = sc[nq][mkv][r] * 0.125f + ((const float*)&mk[mkv])[r];
          vv[mkv][r] = v;
          mx = fmaxf(mx, v);
        }
      mx = fmaxf(mx, __shfl_xor(mx, 16, 64));
      mx = fmaxf(mx, __shfl_xor(mx, 32, 64));
      const float mn = fmaxf(m_st[nq], mx);
      alpha[nq] = __expf(m_st[nq] - mn);
      m_st[nq] = mn;
      float rsum = 0.f;
      for (int mkv = 0; mkv < 4; ++mkv) {
        const float p0 = __expf(vv[mkv][0] - mn);
        const float p1 = __expf(vv[mkv][1] - mn);
        const float p2 = __expf(vv[mkv][2] - mn);
        const float p3 = __expf(vv[mkv][3] - mn);
        rsum += (p0 + p1) + (p2 + p3);
        pk[nq][mkv][0] = pack2bf(p0, p1);
        pk[nq][mkv][1] = pack2bf(p2, p3);
      }
      rsum += __shfl_xor(rsum, 16, 64);
      rsum += __shfl_xor(rsum, 32, 64);
      l_st[nq] = l_st[nq] * alpha[nq] + rsum;
    }

    // rescale accO rows by alpha (shuffle alpha from softmax-layout lanes)
    for (int mq = 0; mq < 2; ++mq)
      for (int r = 0; r < 4; ++r) {
        const float a = __shfl(alpha[mq], (lane & 48) | (quad * 4 + r), 64);
        for (int nd = 0; nd < 4; ++nd) accO[mq][nd][r] *= a;
      }

    // O += P · V : A-frag = pk registers directly (sigma alignment), B = Vts rows
    for (int ks = 0; ks < 2; ++ks) {
      const int kc = ks * 4 + quad;
      bf16x8 vf[4];
      for (int nd = 0; nd < 4; ++nd) {
        const int row = nd * 16 + li;
        vf[nd] = *(const bf16x8*)(Vts + (row * 8 + (kc ^ (row & 7))) * 8);
      }
      for (int mq = 0; mq < 2; ++mq) {
        bf16x8 pf;
        ((unsigned int*)&pf)[0] = pk[mq][2 * ks][0];
        ((unsigned int*)&pf)[1] = pk[mq][2 * ks][1];
        ((unsigned int*)&pf)[2] = pk[mq][2 * ks + 1][0];
        ((unsigned int*)&pf)[3] = pk[mq][2 * ks + 1][1];
        for (int nd = 0; nd < 4; ++nd)
          accO[mq][nd] = __builtin_amdgcn_mfma_f32_16x16x32_bf16(pf, vf[nd], accO[mq][nd], 0, 0, 0);
      }
    }
    __syncthreads();  // K/V LDS reads drained before next staging
  }

  // epilogue: normalize by l (shuffled to accO layout), store bf16
  for (int mq = 0; mq < 2; ++mq)
    for (int r = 0; r < 4; ++r) {
      const float lv = __shfl(l_st[mq], (lane & 48) | (quad * 4 + r), 64);
      const float inv = 1.0f / lv;
      const size_t tok = tokbase + qt * 128 + wq + mq * 16 + quad * 4 + r;
      for (int nd = 0; nd < 4; ++nd)
        outa[tok * HID + h * HDIM + nd * 16 + li] = f2bf(accO[mq][nd][r] * inv);
    }
}

// ---------- launch ----------

extern "C" void kernel_launch(void* const* d_in, const int* in_sizes, int n_in,
                              void* d_out, int out_size, void* d_ws, size_t ws_size,
                              hipStream_t stream) {
  const float* hidden = (const float*)d_in[0];
  const float* mask   = (const float*)d_in[1];
  const float* gamma  = (const float*)d_in[2];
  const float* beta   = (const float*)d_in[3];
  const float* Wqkv   = (const float*)d_in[4];
  const float* bqkv   = (const float*)d_in[5];
  const float* Wout   = (const float*)d_in[6];
  const float* bout   = (const float*)d_in[7];
  float* out = (float*)d_out;

  char* ws = (char*)d_ws;
  ushort* x_bf  = (ushort*)(ws);                       // 16 MB (dead after gemm0)
  ushort* vtb   = (ushort*)(ws);                       // 16 MB (reuses x_bf region)
  ushort* wqkvT = (ushort*)(ws + ((size_t)16 << 20));  //  6 MB
  ushort* woutT = (ushort*)(ws + ((size_t)22 << 20));  //  2 MB
  ushort* qkvb  = (ushort*)(ws + ((size_t)24 << 20));  // 48 MB
  ushort* attnb = (ushort*)(ws + ((size_t)72 << 20));  // 16 MB

  ln_kernel<<<NTOK, 256, 0, stream>>>(hidden, gamma, beta, x_bf);
  transpose_cvt<<<dim3(NQKV / 32, HID / 32), 256, 0, stream>>>(Wqkv, wqkvT, HID, NQKV);
  transpose_cvt<<<dim3(HID / 32, HID / 32), 256, 0, stream>>>(Wout, woutT, HID, HID);
  gemm_bt<0><<<dim3(NQKV / 128, NTOK / 128), 256, 0, stream>>>(
      x_bf, wqkvT, bqkv, nullptr, qkvb, nullptr, NTOK, NQKV, HID);
  v_transpose<<<dim3(SEQ / 64, NHEAD, NB), 256, 0, stream>>>(qkvb, vtb);
  flash_attn<<<dim3(SEQ / 128, NHEAD, NB), 256, 0, stream>>>(qkvb, vtb, mask, attnb);
  gemm_bt<1><<<dim3(HID / 128, NTOK / 128), 256, 0, stream>>>(
      attnb, woutT, bout, hidden, nullptr, out, NTOK, HID, HID);
}